// Round 3
// baseline (1181.621 us; speedup 1.0000x reference)
//
#include <hip/hip_runtime.h>
#include <stdint.h>

#define BB 8
#define NN 4096
#define HH 64
#define C2 128   // [x|h] concat width
#define FW 384   // feature width of Feat

typedef float f32x4 __attribute__((ext_vector_type(4)));
typedef __bf16 bf16x8 __attribute__((ext_vector_type(8)));
typedef unsigned int u32x4 __attribute__((ext_vector_type(4)));

__device__ __forceinline__ unsigned short f2bf(float x) {
  unsigned int u = __float_as_uint(x);
  u += 0x7FFFu + ((u >> 16) & 1u);   // RNE
  return (unsigned short)(u >> 16);
}
__device__ __forceinline__ unsigned int pack2(float a, float b) {
  return (unsigned int)f2bf(a) | ((unsigned int)f2bf(b) << 16);
}
__device__ __forceinline__ bf16x8 mk_frag(f32x4 a0, f32x4 a1) {
  u32x4 u = {pack2(a0.x, a0.y), pack2(a0.z, a0.w), pack2(a1.x, a1.y), pack2(a1.z, a1.w)};
  return __builtin_bit_cast(bf16x8, u);
}
// async global->LDS, 16B/lane, linear dest (wave-uniform base + lane*16)
__device__ __forceinline__ void gl_lds16(const float* g, float* l) {
  __builtin_amdgcn_global_load_lds(
      (const __attribute__((address_space(1))) unsigned int*)g,
      (__attribute__((address_space(3))) unsigned int*)l, 16, 0, 0);
}

// ---------------------------------------------------------------------------
// prepX: x,h [B][N][64] f32 -> XbfT [B][128][N] bf16 (k-major, gemm1 B-panel)
//                             + Feat [B][N][0:128] bf16 (row-major, final A)
// ---------------------------------------------------------------------------
__global__ __launch_bounds__(256) void k_prepX(const float* __restrict__ x,
                                               const float* __restrict__ h,
                                               unsigned short* __restrict__ XbfT,
                                               unsigned short* __restrict__ Feat) {
  __shared__ __align__(16) unsigned short lds[64 * 136];
  const int b = blockIdx.y;
  const int n0 = blockIdx.x * 64;
  const int t = threadIdx.x;
#pragma unroll
  for (int i = 0; i < 4; ++i) {
    int e = t + i * 256;           // 0..1023
    int n = e >> 4, f4 = e & 15;
    size_t src = (((size_t)b * NN + n0 + n) << 6) + f4 * 4;
    f32x4 vx = *(const f32x4*)(x + src);
    f32x4 vh = *(const f32x4*)(h + src);
    unsigned short* px = &lds[n * 136 + f4 * 4];
    px[0] = f2bf(vx.x); px[1] = f2bf(vx.y); px[2] = f2bf(vx.z); px[3] = f2bf(vx.w);
    unsigned short* ph = &lds[n * 136 + 64 + f4 * 4];
    ph[0] = f2bf(vh.x); ph[1] = f2bf(vh.y); ph[2] = f2bf(vh.z); ph[3] = f2bf(vh.w);
  }
  __syncthreads();
  { // XbfT: transposed [f][n] write
    const int f2 = t >> 1, half = t & 1;
    unsigned int wbuf[16];
#pragma unroll
    for (int i = 0; i < 16; ++i) {
      int na = half * 32 + i * 2;
      wbuf[i] = (unsigned int)lds[na * 136 + f2] |
                ((unsigned int)lds[(na + 1) * 136 + f2] << 16);
    }
    size_t off = ((size_t)b * C2 + f2) * NN + n0 + half * 32;
    u32x4* dst = (u32x4*)(XbfT + off);
    u32x4 v0 = {wbuf[0], wbuf[1], wbuf[2], wbuf[3]};     dst[0] = v0;
    u32x4 v1 = {wbuf[4], wbuf[5], wbuf[6], wbuf[7]};     dst[1] = v1;
    u32x4 v2 = {wbuf[8], wbuf[9], wbuf[10], wbuf[11]};   dst[2] = v2;
    u32x4 v3 = {wbuf[12], wbuf[13], wbuf[14], wbuf[15]}; dst[3] = v3;
  }
  { // Feat rows [n][0:128]: 32 contiguous shorts per thread (bugfix: was
    // writing +0 and +16 only, leaving [8,16)+[24,32) poisoned)
    int n = t >> 2, c0 = (t & 3) * 32;
    unsigned short* fd = Feat + ((size_t)b * NN + n0 + n) * FW + c0;
    const unsigned short* sl = &lds[n * 136 + c0];
#pragma unroll
    for (int i = 0; i < 4; ++i)
      *(u32x4*)(fd + 8 * i) = *(const u32x4*)(sl + 8 * i);
  }
}

// ---------------------------------------------------------------------------
// prepW: W1,W2 [3][64][256] f32 -> WcatT [256 o][384 k] bf16
// k-blocks: x->W1[0], h->W2[0], T1x->W1[1], T1h->W2[1], T2x->W1[2], T2h->W2[2]
// ---------------------------------------------------------------------------
__global__ __launch_bounds__(256) void k_prepW(const float* __restrict__ W1,
                                               const float* __restrict__ W2,
                                               unsigned short* __restrict__ WcatT) {
  int tid = blockIdx.x * 256 + threadIdx.x;   // 49152 threads
  int o = tid & 255;
  int kk = (tid >> 8) * 2;
  unsigned int out = 0;
#pragma unroll
  for (int j = 0; j < 2; ++j) {
    int k = kk + j;
    int kb = k >> 6, f = k & 63;
    const float* src = (kb & 1) ? W2 : W1;
    float v = src[(((kb >> 1) * 64 + f) << 8) + o];
    out |= ((unsigned int)f2bf(v)) << (16 * j);
  }
  *(unsigned int*)(WcatT + (size_t)o * FW + kk) = out;
}

// ---------------------------------------------------------------------------
// gemmL<PASS>: P = L_b @ Bpan_b   (Bpan = [B][128][N] bf16, k-major)
//   PASS 1: T1T[b][c][n] = P ; Feat[b][n][128+c] = P
//   PASS 2: Feat[b][n][256+c] = 2*P - T0  (T0 = x|h f32)
// tile 64 x 128, BK=64, 8 waves (4M x 2N), wave tile 16x64.
// A (L, f32) via global_load_lds w/ source XOR-swizzle; B direct global->reg.
// ---------------------------------------------------------------------------
template <int PASS>
__global__ __launch_bounds__(512, 4) void k_gemmL(
    const float* __restrict__ L, const unsigned short* __restrict__ Bpan,
    unsigned short* __restrict__ T1T, unsigned short* __restrict__ Feat,
    const float* __restrict__ xg, const float* __restrict__ hg) {
  __shared__ __align__(16) float As[2][64 * 64];   // 2 x 16 KB
  const int blk = blockIdx.x;
  const int b = blk & 7;                  // XCD-clustered per batch
  const int n0 = (blk >> 3) * 64;
  const int t = threadIdx.x;
  const int w = t >> 6, l = t & 63;
  const int wr = w >> 1, wc = w & 1;      // 4 M-groups x 2 N-groups
  const int l15 = l & 15, l4 = l >> 4;

  const float* Lb = L + ((size_t)b * NN + n0) * NN;
  const unsigned short* Bp = Bpan + (size_t)b * C2 * NN;

  f32x4 acc[4];
  f32x4 z = {0.f, 0.f, 0.f, 0.f};
#pragma unroll
  for (int i = 0; i < 4; ++i) acc[i] = z;

  // stage k-tile kt into buffer p: linear LDS dest, XOR-swizzled global source
#define STAGE(kt, p)                                                        \
  {                                                                         \
    int k0s = (kt) * 64;                                                    \
    _Pragma("unroll") for (int i = 0; i < 2; ++i) {                         \
      int seg = w * 2 + i;                       /* 0..15, 4 rows each */   \
      int r = seg * 4 + (l >> 4);                                           \
      int s = l & 15;                                                       \
      const float* src = Lb + (size_t)r * NN + k0s + ((s ^ (r & 15)) << 2); \
      gl_lds16(src, &As[p][seg * 256]);                                     \
    }                                                                       \
  }

#define COMPUTE(p, kt)                                                      \
  {                                                                         \
    int k0c = (kt) * 64;                                                    \
    u32x4 br[8];                                                            \
    _Pragma("unroll") for (int cf = 0; cf < 4; ++cf)                        \
      _Pragma("unroll") for (int ks = 0; ks < 2; ++ks)                      \
        br[cf * 2 + ks] = *(const u32x4*)(                                  \
            Bp + (size_t)(wc * 64 + cf * 16 + l15) * NN + k0c + ks * 32 + l4 * 8); \
    bf16x8 af[2];                                                           \
    _Pragma("unroll") for (int ks = 0; ks < 2; ++ks) {                      \
      int q = ks * 8 + l4 * 2;                                              \
      int n = wr * 16 + l15;             /* n & 15 == l15 */                \
      f32x4 a0 = *(const f32x4*)&As[p][n * 64 + ((q ^ l15) << 2)];          \
      f32x4 a1 = *(const f32x4*)&As[p][n * 64 + (((q + 1) ^ l15) << 2)];    \
      af[ks] = mk_frag(a0, a1);                                             \
    }                                                                       \
    _Pragma("unroll") for (int ks = 0; ks < 2; ++ks)                        \
      _Pragma("unroll") for (int cf = 0; cf < 4; ++cf)                      \
        acc[cf] = __builtin_amdgcn_mfma_f32_16x16x32_bf16(                  \
            af[ks], __builtin_bit_cast(bf16x8, br[cf * 2 + ks]), acc[cf], 0, 0, 0); \
  }

  STAGE(0, 0);
  __syncthreads();                       // drains stage(0)
#pragma unroll 1
  for (int kt = 0; kt < NN / 64; kt += 2) {
    STAGE(kt + 1, 1);                    // in flight under COMPUTE(0)
    COMPUTE(0, kt);
    __syncthreads();                     // vmcnt(0): buf1 ready
    if (kt + 2 < NN / 64) STAGE(kt + 2, 0);
    COMPUTE(1, kt + 1);
    __syncthreads();
  }
#undef STAGE
#undef COMPUTE

  // epilogue: lane (l15,l4) holds col c = wc*64+cf*16+l15, rows nb+0..3
  const int nb = n0 + wr * 16 + l4 * 4;
#pragma unroll
  for (int cf = 0; cf < 4; ++cf) {
    int c = wc * 64 + cf * 16 + l15;
    f32x4 v = acc[cf];
    if (PASS == 1) {
      *(uint2*)(T1T + ((size_t)b * C2 + c) * NN + nb) =
          make_uint2(pack2(v.x, v.y), pack2(v.z, v.w));
      unsigned short* fr = Feat + ((size_t)b * NN + nb) * FW + 128 + c;
#pragma unroll
      for (int r = 0; r < 4; ++r) fr[(size_t)r * FW] = f2bf(v[r]);
    } else {
      const float* t0p = (c < 64) ? (xg + (((size_t)b * NN + nb) << 6) + c)
                                  : (hg + (((size_t)b * NN + nb) << 6) + (c - 64));
      unsigned short* fr = Feat + ((size_t)b * NN + nb) * FW + 256 + c;
#pragma unroll
      for (int r = 0; r < 4; ++r)
        fr[(size_t)r * FW] = f2bf(2.0f * v[r] - t0p[(size_t)r << 6]);
    }
  }
}

// ---------------------------------------------------------------------------
// final (operand-swapped, no LDS, no barriers):
//   D[gate o][n] = sum_k WcatT[o][k] * Feat[n][k]; then LSTM gates.
// block = 64 n-rows, 4 waves x 16 n each; per wave acc[16] covers 256 gates.
// ---------------------------------------------------------------------------
__global__ __launch_bounds__(256) void k_final(
    const unsigned short* __restrict__ Feat, const unsigned short* __restrict__ WcatT,
    const float* __restrict__ b1, const float* __restrict__ b2,
    const float* __restrict__ c_cur, float* __restrict__ out) {
  const int t = threadIdx.x, w = t >> 6, l = t & 63;
  const int l15 = l & 15, l4 = l >> 4;
  const int b = blockIdx.x >> 6;
  const int n0 = (blockIdx.x & 63) * 64;
  const int n = n0 + w * 16 + l15;

  const unsigned short* frow = Feat + ((size_t)b * NN + n) * FW + l4 * 8;
  f32x4 acc[16];
  f32x4 z = {0.f, 0.f, 0.f, 0.f};
#pragma unroll
  for (int i = 0; i < 16; ++i) acc[i] = z;

#pragma unroll 1
  for (int ks = 0; ks < 12; ++ks) {
    bf16x8 bf = *(const bf16x8*)(frow + ks * 32);
#pragma unroll
    for (int fA = 0; fA < 16; ++fA) {
      bf16x8 aw = *(const bf16x8*)(WcatT + (size_t)(fA * 16 + l15) * FW + ks * 32 + l4 * 8);
      acc[fA] = __builtin_amdgcn_mfma_f32_16x16x32_bf16(aw, bf, acc[fA], 0, 0, 0);
    }
  }

  // lane holds col n; acc[fA] reg r -> gate o = fA*16 + l4*4 + r
  const size_t base_n = (((size_t)b * NN + n) << 6);
#pragma unroll
  for (int fA = 0; fA < 4; ++fA) {
#pragma unroll
    for (int r = 0; r < 4; ++r) {
      int j = fA * 16 + l4 * 4 + r;
      float ii = acc[fA][r]      + b1[j]       + b2[j];
      float ff = acc[fA + 4][r]  + b1[64 + j]  + b2[64 + j];
      float oo = acc[fA + 8][r]  + b1[128 + j] + b2[128 + j];
      float gg = acc[fA + 12][r] + b1[192 + j] + b2[192 + j];
      ii = 1.0f / (1.0f + __expf(-ii));
      ff = 1.0f / (1.0f + __expf(-ff));
      oo = 1.0f / (1.0f + __expf(-oo));
      gg = tanhf(gg);
      float cn = ff * c_cur[base_n + j] + ii * gg;
      float hn = oo * tanhf(cn);
      out[base_n + j] = hn;
      out[(size_t)BB * NN * HH + base_n + j] = cn;
    }
  }
}

// ---------------------------------------------------------------------------
extern "C" void kernel_launch(void* const* d_in, const int* in_sizes, int n_in,
                              void* d_out, int out_size, void* d_ws, size_t ws_size,
                              hipStream_t stream) {
  const float* x  = (const float*)d_in[0];
  const float* L  = (const float*)d_in[1];
  const float* h  = (const float*)d_in[2];
  const float* c  = (const float*)d_in[3];
  const float* W1 = (const float*)d_in[4];
  const float* b1 = (const float*)d_in[5];
  const float* W2 = (const float*)d_in[6];
  const float* b2 = (const float*)d_in[7];
  char* ws = (char*)d_ws;
  unsigned short* XbfT  = (unsigned short*)(ws);                        // 8 MB
  unsigned short* T1T   = (unsigned short*)(ws + (size_t)(8u << 20));   // 8 MB
  unsigned short* Feat  = (unsigned short*)(ws + (size_t)(16u << 20));  // 24 MB
  unsigned short* WcatT = (unsigned short*)(ws + (size_t)(40u << 20));  // 192 KB
  float* out = (float*)d_out;

  k_prepX<<<dim3(64, 8), 256, 0, stream>>>(x, h, XbfT, Feat);
  k_prepW<<<dim3(192), 256, 0, stream>>>(W1, W2, WcatT);
  k_gemmL<1><<<dim3(512), 512, 0, stream>>>(L, XbfT, T1T, Feat, nullptr, nullptr);
  k_gemmL<2><<<dim3(512), 512, 0, stream>>>(L, T1T, nullptr, Feat, x, h);
  k_final<<<dim3(512), 256, 0, stream>>>(Feat, WcatT, b1, b2, c, out);
}